// Round 8
// baseline (3477.961 us; speedup 1.0000x reference)
//
#include <hip/hip_runtime.h>
#include <hip/hip_cooperative_groups.h>

namespace cg = cooperative_groups;

// LSTM_73512660239038: 64-step LSTM, H=B=1024, INPUT_DIM=1.
// R8: ONE persistent cooperative kernel for all 64 steps. W fragments live in
// VGPRs (128/thread) loaded ONCE from a fragment-ordered Wreg layout; c lives
// in VGPRs; per-step only h crosses global. 8 waves = (gate, K-half); K-half
// partials combined in the z-exchange (two-phase write/add). fp16 numerics.

typedef _Float16 f16;
typedef __attribute__((ext_vector_type(8))) _Float16 f16x8;
typedef __attribute__((ext_vector_type(4))) float f32x4;

typedef const __attribute__((address_space(1))) unsigned char* gbl_ptr_t;
typedef __attribute__((address_space(3))) unsigned char* lds_ptr_t;

__device__ __forceinline__ float fsig(float z) {
  return 1.0f / (1.0f + __expf(-z));
}
__device__ __forceinline__ float ftanh(float z) {
  float a = fabsf(z);
  float e = __expf(-2.0f * a);
  float t = (1.0f - e) / (1.0f + e);
  return z < 0.0f ? -t : t;
}

// ---------------- prep: build fragment-ordered Wreg + w0 + WPf ----------------
// Wreg flat index i (22 bits): e=i&7, l=(i>>3)&63, f=(i>>9)&31, w=(i>>14)&7,
// hr=i>>17. f = m*16 + ktl*2 + ks. Then row(gate)=hr*32+m*16+(l&15),
// k = kh*512 + ktl*64 + ks*32 + (l>>4)*8 + e. Source w_gate[row][k+1] ([H][H+1]).
__global__ __launch_bounds__(256) void k_prep(
    const float* __restrict__ wg, const float* __restrict__ wi,
    const float* __restrict__ wf, const float* __restrict__ wo,
    const float* __restrict__ wp,
    f16* __restrict__ Wreg, float* __restrict__ w0, f16* __restrict__ WPf) {
  const int NR = 1 << 22;
  const int NW0 = 4096;
  const int NP = 1 << 20;
  int i = blockIdx.x * blockDim.x + threadIdx.x;
  const int stride = gridDim.x * blockDim.x;
  for (; i < NR + NW0 + NP; i += stride) {
    if (i < NR) {
      const int e = i & 7, l = (i >> 3) & 63, f = (i >> 9) & 31;
      const int w = (i >> 14) & 7, hr = i >> 17;
      const int gate = w >> 1, kh = w & 1;
      const int m = f >> 4, ktl = (f >> 1) & 7, ks = f & 1;
      const int row = hr * 32 + m * 16 + (l & 15);
      const int k = kh * 512 + ktl * 64 + ks * 32 + ((l >> 4) << 3) + e;
      const float* ws = gate == 0 ? wg : gate == 1 ? wi : gate == 2 ? wf : wo;
      Wreg[i] = (f16)ws[row * 1025 + k + 1];
    } else if (i < NR + NW0) {
      const int j = i - NR;
      const int gate = j >> 10, r = j & 1023;
      const float* ws = gate == 0 ? wg : gate == 1 ? wi : gate == 2 ? wf : wo;
      w0[j] = ws[r * 1025];                 // x-weight column, fp32
    } else {
      WPf[i - NR - NW0] = (f16)wp[i - NR - NW0];
    }
  }
}

// ---------------- persistent all-steps kernel ----------------
// grid 256 (1 block/CU): bt = bx&7 (XCD-aligned btile, 128 b), hr = bx>>3 (32 h-rows).
// 8 waves: gate = wid>>1, kh = wid&1. Wave tile: 32 rows x 128 b over K-half 512.
// LDS: [0,64K) h-stage dbuf (2 x tile[kh][128 b][64 k] f16), [64K,128K) zl
// [4][128][32] f32, then bias[4][128] f32 + w0l[4][32] f32.
__global__ __launch_bounds__(512, 2) void k_persist(
    const f16* __restrict__ Wreg, const float* __restrict__ w0,
    const float* __restrict__ x,
    const float* __restrict__ bg, const float* __restrict__ bi,
    const float* __restrict__ bff, const float* __restrict__ bo,
    f16* __restrict__ h0, f16* __restrict__ h1) {
  __shared__ alignas(16) unsigned char smem[133632];
  const int tid = threadIdx.x;
  const int wid = tid >> 6;
  const int lane = tid & 63;
  const int gate = wid >> 1;
  const int kh = wid & 1;
  const int bt = blockIdx.x & 7;            // same btile -> same XCD (h L2 reuse)
  const int hr = blockIdx.x >> 3;
  const int b0 = bt * 128;
  const int hr0 = hr * 32;

  // ---- load W fragments ONCE (coalesced: Wreg is fragment-ordered) ----
  f16x8 W[2][8][2];
  {
    const f16* wb = Wreg + (((long)(hr * 8 + wid) * 32) << 9) + lane * 8;
#pragma unroll
    for (int m = 0; m < 2; ++m)
#pragma unroll
      for (int ktl = 0; ktl < 8; ++ktl)
#pragma unroll
        for (int ks = 0; ks < 2; ++ks)
          W[m][ktl][ks] = *(const f16x8*)(wb + ((m * 16 + ktl * 2 + ks) << 9));
  }

  // ---- one-time LDS: biases + w0 slice ----
  float* zl = (float*)(smem + 65536);
  float* biasl = (float*)(smem + 131072);   // [4][128]
  float* w0l = (float*)(smem + 131072 + 2048);  // [4][32]
  {
    const int g = tid >> 7, bb = tid & 127;
    const float* bsrc = g == 0 ? bg : g == 1 ? bi : g == 2 ? bff : bo;
    biasl[g * 128 + bb] = bsrc[b0 + bb];
    if (tid < 128) {
      const int g2 = tid >> 5, r = tid & 31;
      w0l[g2 * 32 + r] = w0[g2 * 1024 + hr0 + r];
    }
  }

  // ---- h-stage chunk decode: 2048 chunks of 16B per 32KB tile, 4/thread ----
  long boffc[4];
  int ldsoc[4];
#pragma unroll
  for (int s = 0; s < 4; ++s) {
    const int ch = s * 512 + tid;
    const int khc = ch >> 10;
    const int r = (ch >> 3) & 127;
    const int sl = ch & 7;
    const int sg = sl ^ (r & 7);            // swizzle on the GLOBAL source
    boffc[s] = ((long)(b0 + r) << 10) + khc * 512 + sg * 8;
    ldsoc[s] = ch * 16;
  }

  float creg[8];
#pragma unroll
  for (int q = 0; q < 8; ++q) creg[q] = 0.f;

  cg::grid_group grid = cg::this_grid();
  __syncthreads();                          // biasl/w0l ready

  const f16* Hi = h0;
  f16* Ho = h1;

  for (int t = 0; t < 64; ++t) {
    // ---- prologue: stage ktl=0 tile ----
#pragma unroll
    for (int s = 0; s < 4; ++s)
      __builtin_amdgcn_global_load_lds((gbl_ptr_t)(const void*)(Hi + boffc[s]),
                                       (lds_ptr_t)(void*)(smem + ldsoc[s]), 16, 0, 0);
    __syncthreads();                        // drains vmcnt -> buf0 ready

    f32x4 acc[2][8];
#pragma unroll
    for (int m = 0; m < 2; ++m)
#pragma unroll
      for (int n = 0; n < 8; ++n) acc[m][n] = (f32x4){0.f, 0.f, 0.f, 0.f};

#pragma unroll
    for (int ktl = 0; ktl < 8; ++ktl) {
      const unsigned pb = (ktl & 1) * 32768;
      if (ktl < 7) {
        const unsigned nb = ((ktl + 1) & 1) * 32768;
        const int k0 = (ktl + 1) << 6;
#pragma unroll
        for (int s = 0; s < 4; ++s)
          __builtin_amdgcn_global_load_lds((gbl_ptr_t)(const void*)(Hi + boffc[s] + k0),
                                           (lds_ptr_t)(void*)(smem + nb + ldsoc[s]), 16, 0, 0);
      }
      __builtin_amdgcn_s_setprio(1);
#pragma unroll
      for (int ks = 0; ks < 2; ++ks) {
        const int s8 = ks * 4 + (lane >> 4);
#pragma unroll
        for (int n = 0; n < 8; ++n) {
          const int trb = n * 16 + (lane & 15);
          const unsigned offb = pb + kh * 16384 + trb * 128 + ((s8 ^ (trb & 7)) << 4);
          const f16x8 bF = *(const f16x8*)(smem + offb);
#pragma unroll
          for (int m = 0; m < 2; ++m)
            acc[m][n] = __builtin_amdgcn_mfma_f32_16x16x32_f16(W[m][ktl][ks], bF,
                                                               acc[m][n], 0, 0, 0);
        }
      }
      __builtin_amdgcn_s_setprio(0);
      __syncthreads();
    }

    // ---- z-exchange: two-phase (kh=0 write, kh=1 add), swizzled r ----
    if (kh == 0) {
#pragma unroll
      for (int n = 0; n < 8; ++n) {
        const int b = n * 16 + (lane & 15);
#pragma unroll
        for (int m = 0; m < 2; ++m)
#pragma unroll
          for (int j = 0; j < 4; ++j) {
            const int r = m * 16 + (lane >> 4) * 4 + j;
            const int rs = (r ^ ((b & 7) << 2)) ^ ((b >> 3) & 1);
            zl[gate * 4096 + b * 32 + rs] = acc[m][n][j];
          }
      }
    }
    __syncthreads();
    if (kh == 1) {
#pragma unroll
      for (int n = 0; n < 8; ++n) {
        const int b = n * 16 + (lane & 15);
#pragma unroll
        for (int m = 0; m < 2; ++m)
#pragma unroll
          for (int j = 0; j < 4; ++j) {
            const int r = m * 16 + (lane >> 4) * 4 + j;
            const int rs = (r ^ ((b & 7) << 2)) ^ ((b >> 3) & 1);
            zl[gate * 4096 + b * 32 + rs] += acc[m][n][j];
          }
      }
    }
    __syncthreads();

    // ---- elementwise gates; bias indexed by BATCH column (ref quirk) ----
#pragma unroll
    for (int q = 0; q < 8; ++q) {
      const int idx = q * 512 + tid;
      const int r = idx & 31, bb = idx >> 5;
      const int rs = (r ^ ((bb & 7) << 2)) ^ ((bb >> 3) & 1);
      float zg = zl[bb * 32 + rs];
      float zi = zl[4096 + bb * 32 + rs];
      float zf = zl[8192 + bb * 32 + rs];
      float zo = zl[12288 + bb * 32 + rs];
      const float xv = x[(b0 + bb) * 64 + t];
      zg += w0l[r] * xv + biasl[bb];
      zi += w0l[32 + r] * xv + biasl[128 + bb];
      zf += w0l[64 + r] * xv + biasl[256 + bb];
      zo += w0l[96 + r] * xv + biasl[384 + bb];
      const float g = ftanh(zg), ii = fsig(zi), ff = fsig(zf), oo = fsig(zo);
      const float c2 = g * ii + creg[q] * ff;
      creg[q] = c2;
      const float h2 = ftanh(c2) * oo;
      Ho[(long)(b0 + bb) * 1024 + hr0 + r] = (f16)h2;
    }

    grid.sync();                            // h(t+1) visible grid-wide
    const f16* tmp = Hi;
    Hi = Ho;
    Ho = (f16*)tmp;
  }
}

// ---------------- final projection: out[b][r] = hs[b,:]·wp[r,:] + bp[r] ----------------
__global__ __launch_bounds__(256) void k_proj(
    const f16* __restrict__ H, const f16* __restrict__ WPf,
    const float* __restrict__ bp, float* __restrict__ out) {
  __shared__ alignas(16) unsigned char smem[32768];
  const int tid = threadIdx.x;
  const int wid = tid >> 6;
  const int lane = tid & 63;
  const int b0 = (blockIdx.x >> 3) * 128;   // M = batch
  const int r0 = (blockIdx.x & 7) * 128;    // N = output row

  f32x4 acc[2][8];
#pragma unroll
  for (int m = 0; m < 2; ++m)
#pragma unroll
    for (int n = 0; n < 8; ++n) acc[m][n] = (f32x4){0.f, 0.f, 0.f, 0.f};

  for (int kt = 0; kt < 16; ++kt) {
    const int k0 = kt << 6;
    __syncthreads();
#pragma unroll
    for (int j = 0; j < 4; ++j) {
      const int i = wid * 4 + j;
      const int ch = i * 64 + lane;
      const int row = ch >> 3;
      const int sl = ch & 7;
      const int sg = sl ^ (row & 7);
      const long aoff = ((long)(b0 + row) << 10) + k0 + sg * 8;
      const long boff = ((long)(r0 + row) << 10) + k0 + sg * 8;
      __builtin_amdgcn_global_load_lds((gbl_ptr_t)(const void*)(H + aoff),
                                       (lds_ptr_t)(void*)(smem + i * 1024), 16, 0, 0);
      __builtin_amdgcn_global_load_lds((gbl_ptr_t)(const void*)(WPf + boff),
                                       (lds_ptr_t)(void*)(smem + 16384 + i * 1024), 16, 0, 0);
    }
    __syncthreads();
#pragma unroll
    for (int ks = 0; ks < 2; ++ks) {
      const int slot = (ks << 2) + (lane >> 4);
      f16x8 aF[2];
#pragma unroll
      for (int m = 0; m < 2; ++m) {
        const int tr = wid * 32 + m * 16 + (lane & 15);
        const int off = tr * 128 + ((slot ^ (tr & 7)) << 4);
        aF[m] = *(const f16x8*)(smem + off);
      }
#pragma unroll
      for (int n = 0; n < 8; ++n) {
        const int tr = n * 16 + (lane & 15);
        const int off = tr * 128 + ((slot ^ (tr & 7)) << 4);
        const f16x8 bF = *(const f16x8*)(smem + 16384 + off);
#pragma unroll
        for (int m = 0; m < 2; ++m) {
          acc[m][n] = __builtin_amdgcn_mfma_f32_16x16x32_f16(aF[m], bF, acc[m][n], 0, 0, 0);
        }
      }
    }
  }
#pragma unroll
  for (int n = 0; n < 8; ++n) {
    const int rr = r0 + n * 16 + (lane & 15);
    const float bpv = bp[rr];
#pragma unroll
    for (int m = 0; m < 2; ++m) {
#pragma unroll
      for (int j = 0; j < 4; ++j) {
        const int bbb = b0 + wid * 32 + m * 16 + (lane >> 4) * 4 + j;
        out[(long)bbb * 1024 + rr] = acc[m][n][j] + bpv;
      }
    }
  }
}

extern "C" void kernel_launch(void* const* d_in, const int* in_sizes, int n_in,
                              void* d_out, int out_size, void* d_ws, size_t ws_size,
                              hipStream_t stream) {
  (void)in_sizes; (void)n_in; (void)out_size; (void)ws_size;
  const float* x  = (const float*)d_in[0];
  const float* wg = (const float*)d_in[1];
  const float* bg = (const float*)d_in[2];
  const float* wi = (const float*)d_in[3];
  const float* bi = (const float*)d_in[4];
  const float* wf = (const float*)d_in[5];
  const float* bf = (const float*)d_in[6];
  const float* wo = (const float*)d_in[7];
  const float* bo = (const float*)d_in[8];
  const float* wp = (const float*)d_in[9];
  const float* bp = (const float*)d_in[10];

  char* ws = (char*)d_ws;
  size_t off = 0;
  auto alloc = [&](size_t bytes) {
    char* p = ws + off;
    off += (bytes + 255) & ~(size_t)255;
    return p;
  };
  f16*   Wreg = (f16*)alloc(8388608);   // fragment-ordered W, fp16
  f16*   WPf  = (f16*)alloc(2097152);   // [1024][1024] fp16
  float* w0   = (float*)alloc(16384);   // [4][1024] x-weight col fp32
  f16*   h0   = (f16*)alloc(2097152);   // h [B][H] fp16
  f16*   h1   = (f16*)alloc(2097152);

  hipMemsetAsync(h0, 0, 2097152, stream);

  k_prep<<<2048, 256, 0, stream>>>(wg, wi, wf, wo, wp, Wreg, w0, WPf);

  {
    const f16* Wreg_c = Wreg;
    const float* w0_c = w0;
    void* args[] = {(void*)&Wreg_c, (void*)&w0_c, (void*)&x,
                    (void*)&bg, (void*)&bi, (void*)&bf, (void*)&bo,
                    (void*)&h0, (void*)&h1};
    hipLaunchCooperativeKernel((const void*)k_persist, dim3(256), dim3(512),
                               args, 0, stream);
  }
  // t=63 (odd) writes h0
  k_proj<<<64, 256, 0, stream>>>(h0, WPf, bp, (float*)d_out);
}

// Round 9
// 3477.384 us; speedup vs baseline: 1.0002x; 1.0002x over previous
//
#include <hip/hip_runtime.h>
#include <hip/hip_cooperative_groups.h>

namespace cg = cooperative_groups;

// LSTM_73512660239038: 64-step LSTM, H=B=1024, INPUT_DIM=1.
// R9 = R8 + W-residency fix: the 32 W fragments (128 VGPRs) are pinned with
// asm "+v" after the one-time load so the allocator cannot sink the loads
// into the 64-step loop (R8 failure: VGPR=128, FETCH 1.5GB = W refetched).
// __launch_bounds__(512) (cap 256), 32-bit h offsets, unroll-1 t-loop.

typedef _Float16 f16;
typedef __attribute__((ext_vector_type(8))) _Float16 f16x8;
typedef __attribute__((ext_vector_type(4))) float f32x4;

typedef const __attribute__((address_space(1))) unsigned char* gbl_ptr_t;
typedef __attribute__((address_space(3))) unsigned char* lds_ptr_t;

__device__ __forceinline__ float fsig(float z) {
  return 1.0f / (1.0f + __expf(-z));
}
__device__ __forceinline__ float ftanh(float z) {
  float a = fabsf(z);
  float e = __expf(-2.0f * a);
  float t = (1.0f - e) / (1.0f + e);
  return z < 0.0f ? -t : t;
}

// ---------------- prep: build fragment-ordered Wreg + w0 + WPf ----------------
// Wreg flat index i: e=i&7, l=(i>>3)&63, f=(i>>9)&31, w=(i>>14)&7, hr=i>>17.
// f = m*16 + ktl*2 + ks; row(gate)=hr*32+m*16+(l&15);
// k = kh*512 + ktl*64 + ks*32 + (l>>4)*8 + e. Source w_gate[row][k+1].
__global__ __launch_bounds__(256) void k_prep(
    const float* __restrict__ wg, const float* __restrict__ wi,
    const float* __restrict__ wf, const float* __restrict__ wo,
    const float* __restrict__ wp,
    f16* __restrict__ Wreg, float* __restrict__ w0, f16* __restrict__ WPf) {
  const int NR = 1 << 22;
  const int NW0 = 4096;
  const int NP = 1 << 20;
  int i = blockIdx.x * blockDim.x + threadIdx.x;
  const int stride = gridDim.x * blockDim.x;
  for (; i < NR + NW0 + NP; i += stride) {
    if (i < NR) {
      const int e = i & 7, l = (i >> 3) & 63, f = (i >> 9) & 31;
      const int w = (i >> 14) & 7, hr = i >> 17;
      const int gate = w >> 1, kh = w & 1;
      const int m = f >> 4, ktl = (f >> 1) & 7, ks = f & 1;
      const int row = hr * 32 + m * 16 + (l & 15);
      const int k = kh * 512 + ktl * 64 + ks * 32 + ((l >> 4) << 3) + e;
      const float* ws = gate == 0 ? wg : gate == 1 ? wi : gate == 2 ? wf : wo;
      Wreg[i] = (f16)ws[row * 1025 + k + 1];
    } else if (i < NR + NW0) {
      const int j = i - NR;
      const int gate = j >> 10, r = j & 1023;
      const float* ws = gate == 0 ? wg : gate == 1 ? wi : gate == 2 ? wf : wo;
      w0[j] = ws[r * 1025];                 // x-weight column, fp32
    } else {
      WPf[i - NR - NW0] = (f16)wp[i - NR - NW0];
    }
  }
}

// ---------------- persistent all-steps kernel ----------------
// grid 256 (1 block/CU): bt = bx&7 (XCD-aligned btile, 128 b), hr = bx>>3.
// 8 waves: gate = wid>>1, kh = wid&1. Wave tile: 32 rows x 128 b, K-half 512.
// LDS: [0,64K) h-stage dbuf, [64K,128K) zl [4][128][32] f32, then bias+w0.
__global__ __launch_bounds__(512) void k_persist(
    const f16* __restrict__ Wreg, const float* __restrict__ w0,
    const float* __restrict__ x,
    const float* __restrict__ bg, const float* __restrict__ bi,
    const float* __restrict__ bff, const float* __restrict__ bo,
    f16* __restrict__ h0, f16* __restrict__ h1) {
  __shared__ alignas(16) unsigned char smem[133632];
  const int tid = threadIdx.x;
  const int wid = tid >> 6;
  const int lane = tid & 63;
  const int gate = wid >> 1;
  const int kh = wid & 1;
  const int bt = blockIdx.x & 7;            // same btile -> same XCD (h L2 reuse)
  const int hr = blockIdx.x >> 3;
  const int b0 = bt * 128;
  const int hr0 = hr * 32;

  // ---- load W fragments ONCE (coalesced: Wreg is fragment-ordered) ----
  f16x8 W[2][8][2];
  {
    const f16* wb = Wreg + (((long)(hr * 8 + wid) * 32) << 9) + lane * 8;
#pragma unroll
    for (int m = 0; m < 2; ++m)
#pragma unroll
      for (int ktl = 0; ktl < 8; ++ktl)
#pragma unroll
        for (int ks = 0; ks < 2; ++ks)
          W[m][ktl][ks] = *(const f16x8*)(wb + ((m * 16 + ktl * 2 + ks) << 9));
  }
  // PIN: make each fragment asm-defined so the loads cannot be sunk into the
  // t-loop (R8: allocator rematerialized them -> 1.5GB/dispatch W refetch).
#pragma unroll
  for (int m = 0; m < 2; ++m)
#pragma unroll
    for (int ktl = 0; ktl < 8; ++ktl)
#pragma unroll
      for (int ks = 0; ks < 2; ++ks)
        asm volatile("" : "+v"(W[m][ktl][ks]));

  // ---- one-time LDS: biases + w0 slice ----
  float* zl = (float*)(smem + 65536);
  float* biasl = (float*)(smem + 131072);   // [4][128]
  float* w0l = (float*)(smem + 131072 + 2048);  // [4][32]
  {
    const int g = tid >> 7, bb = tid & 127;
    const float* bsrc = g == 0 ? bg : g == 1 ? bi : g == 2 ? bff : bo;
    biasl[g * 128 + bb] = bsrc[b0 + bb];
    if (tid < 128) {
      const int g2 = tid >> 5, r = tid & 31;
      w0l[g2 * 32 + r] = w0[g2 * 1024 + hr0 + r];
    }
  }

  // ---- h-stage chunk decode: 2048 chunks of 16B per 32KB tile, 4/thread ----
  int boffc[4];                             // element offsets into h (fits int)
  int ldsoc[4];
#pragma unroll
  for (int s = 0; s < 4; ++s) {
    const int ch = s * 512 + tid;
    const int khc = ch >> 10;
    const int r = (ch >> 3) & 127;
    const int sl = ch & 7;
    const int sg = sl ^ (r & 7);            // swizzle on the GLOBAL source
    boffc[s] = ((b0 + r) << 10) + khc * 512 + sg * 8;
    ldsoc[s] = ch * 16;
  }

  float creg[8];
#pragma unroll
  for (int q = 0; q < 8; ++q) creg[q] = 0.f;

  cg::grid_group grid = cg::this_grid();
  __syncthreads();                          // biasl/w0l ready

  const f16* Hi = h0;
  f16* Ho = h1;

#pragma unroll 1
  for (int t = 0; t < 64; ++t) {
    // ---- prologue: stage ktl=0 tile ----
#pragma unroll
    for (int s = 0; s < 4; ++s)
      __builtin_amdgcn_global_load_lds((gbl_ptr_t)(const void*)(Hi + boffc[s]),
                                       (lds_ptr_t)(void*)(smem + ldsoc[s]), 16, 0, 0);
    __syncthreads();                        // drains vmcnt -> buf0 ready

    f32x4 acc[2][8];
#pragma unroll
    for (int m = 0; m < 2; ++m)
#pragma unroll
      for (int n = 0; n < 8; ++n) acc[m][n] = (f32x4){0.f, 0.f, 0.f, 0.f};

#pragma unroll
    for (int ktl = 0; ktl < 8; ++ktl) {
      const unsigned pb = (ktl & 1) * 32768;
      if (ktl < 7) {
        const unsigned nb = ((ktl + 1) & 1) * 32768;
        const int k0 = (ktl + 1) << 6;
#pragma unroll
        for (int s = 0; s < 4; ++s)
          __builtin_amdgcn_global_load_lds((gbl_ptr_t)(const void*)(Hi + boffc[s] + k0),
                                           (lds_ptr_t)(void*)(smem + nb + ldsoc[s]), 16, 0, 0);
      }
      __builtin_amdgcn_s_setprio(1);
#pragma unroll
      for (int ks = 0; ks < 2; ++ks) {
        const int s8 = ks * 4 + (lane >> 4);
#pragma unroll
        for (int n = 0; n < 8; ++n) {
          const int trb = n * 16 + (lane & 15);
          const unsigned offb = pb + kh * 16384 + trb * 128 + ((s8 ^ (trb & 7)) << 4);
          const f16x8 bF = *(const f16x8*)(smem + offb);
#pragma unroll
          for (int m = 0; m < 2; ++m)
            acc[m][n] = __builtin_amdgcn_mfma_f32_16x16x32_f16(W[m][ktl][ks], bF,
                                                               acc[m][n], 0, 0, 0);
        }
      }
      __builtin_amdgcn_s_setprio(0);
      __syncthreads();
    }

    // ---- z-exchange: two-phase (kh=0 write, kh=1 add), swizzled r ----
    if (kh == 0) {
#pragma unroll
      for (int n = 0; n < 8; ++n) {
        const int b = n * 16 + (lane & 15);
#pragma unroll
        for (int m = 0; m < 2; ++m)
#pragma unroll
          for (int j = 0; j < 4; ++j) {
            const int r = m * 16 + (lane >> 4) * 4 + j;
            const int rs = (r ^ ((b & 7) << 2)) ^ ((b >> 3) & 1);
            zl[gate * 4096 + b * 32 + rs] = acc[m][n][j];
          }
      }
    }
    __syncthreads();
    if (kh == 1) {
#pragma unroll
      for (int n = 0; n < 8; ++n) {
        const int b = n * 16 + (lane & 15);
#pragma unroll
        for (int m = 0; m < 2; ++m)
#pragma unroll
          for (int j = 0; j < 4; ++j) {
            const int r = m * 16 + (lane >> 4) * 4 + j;
            const int rs = (r ^ ((b & 7) << 2)) ^ ((b >> 3) & 1);
            zl[gate * 4096 + b * 32 + rs] += acc[m][n][j];
          }
      }
    }
    __syncthreads();

    // ---- elementwise gates; bias indexed by BATCH column (ref quirk) ----
#pragma unroll
    for (int q = 0; q < 8; ++q) {
      const int idx = q * 512 + tid;
      const int r = idx & 31, bb = idx >> 5;
      const int rs = (r ^ ((bb & 7) << 2)) ^ ((bb >> 3) & 1);
      float zg = zl[bb * 32 + rs];
      float zi = zl[4096 + bb * 32 + rs];
      float zf = zl[8192 + bb * 32 + rs];
      float zo = zl[12288 + bb * 32 + rs];
      const float xv = x[(b0 + bb) * 64 + t];
      zg += w0l[r] * xv + biasl[bb];
      zi += w0l[32 + r] * xv + biasl[128 + bb];
      zf += w0l[64 + r] * xv + biasl[256 + bb];
      zo += w0l[96 + r] * xv + biasl[384 + bb];
      const float g = ftanh(zg), ii = fsig(zi), ff = fsig(zf), oo = fsig(zo);
      const float c2 = g * ii + creg[q] * ff;
      creg[q] = c2;
      const float h2 = ftanh(c2) * oo;
      Ho[(long)(b0 + bb) * 1024 + hr0 + r] = (f16)h2;
    }

    grid.sync();                            // h(t+1) visible grid-wide
    const f16* tmp = Hi;
    Hi = Ho;
    Ho = (f16*)tmp;
  }
}

// ---------------- final projection: out[b][r] = hs[b,:]·wp[r,:] + bp[r] ----------------
__global__ __launch_bounds__(256) void k_proj(
    const f16* __restrict__ H, const f16* __restrict__ WPf,
    const float* __restrict__ bp, float* __restrict__ out) {
  __shared__ alignas(16) unsigned char smem[32768];
  const int tid = threadIdx.x;
  const int wid = tid >> 6;
  const int lane = tid & 63;
  const int b0 = (blockIdx.x >> 3) * 128;   // M = batch
  const int r0 = (blockIdx.x & 7) * 128;    // N = output row

  f32x4 acc[2][8];
#pragma unroll
  for (int m = 0; m < 2; ++m)
#pragma unroll
    for (int n = 0; n < 8; ++n) acc[m][n] = (f32x4){0.f, 0.f, 0.f, 0.f};

  for (int kt = 0; kt < 16; ++kt) {
    const int k0 = kt << 6;
    __syncthreads();
#pragma unroll
    for (int j = 0; j < 4; ++j) {
      const int i = wid * 4 + j;
      const int ch = i * 64 + lane;
      const int row = ch >> 3;
      const int sl = ch & 7;
      const int sg = sl ^ (row & 7);
      const long aoff = ((long)(b0 + row) << 10) + k0 + sg * 8;
      const long boff = ((long)(r0 + row) << 10) + k0 + sg * 8;
      __builtin_amdgcn_global_load_lds((gbl_ptr_t)(const void*)(H + aoff),
                                       (lds_ptr_t)(void*)(smem + i * 1024), 16, 0, 0);
      __builtin_amdgcn_global_load_lds((gbl_ptr_t)(const void*)(WPf + boff),
                                       (lds_ptr_t)(void*)(smem + 16384 + i * 1024), 16, 0, 0);
    }
    __syncthreads();
#pragma unroll
    for (int ks = 0; ks < 2; ++ks) {
      const int slot = (ks << 2) + (lane >> 4);
      f16x8 aF[2];
#pragma unroll
      for (int m = 0; m < 2; ++m) {
        const int tr = wid * 32 + m * 16 + (lane & 15);
        const int off = tr * 128 + ((slot ^ (tr & 7)) << 4);
        aF[m] = *(const f16x8*)(smem + off);
      }
#pragma unroll
      for (int n = 0; n < 8; ++n) {
        const int tr = n * 16 + (lane & 15);
        const int off = tr * 128 + ((slot ^ (tr & 7)) << 4);
        const f16x8 bF = *(const f16x8*)(smem + 16384 + off);
#pragma unroll
        for (int m = 0; m < 2; ++m) {
          acc[m][n] = __builtin_amdgcn_mfma_f32_16x16x32_f16(aF[m], bF, acc[m][n], 0, 0, 0);
        }
      }
    }
  }
#pragma unroll
  for (int n = 0; n < 8; ++n) {
    const int rr = r0 + n * 16 + (lane & 15);
    const float bpv = bp[rr];
#pragma unroll
    for (int m = 0; m < 2; ++m) {
#pragma unroll
      for (int j = 0; j < 4; ++j) {
        const int bbb = b0 + wid * 32 + m * 16 + (lane >> 4) * 4 + j;
        out[(long)bbb * 1024 + rr] = acc[m][n][j] + bpv;
      }
    }
  }
}

extern "C" void kernel_launch(void* const* d_in, const int* in_sizes, int n_in,
                              void* d_out, int out_size, void* d_ws, size_t ws_size,
                              hipStream_t stream) {
  (void)in_sizes; (void)n_in; (void)out_size; (void)ws_size;
  const float* x  = (const float*)d_in[0];
  const float* wg = (const float*)d_in[1];
  const float* bg = (const float*)d_in[2];
  const float* wi = (const float*)d_in[3];
  const float* bi = (const float*)d_in[4];
  const float* wf = (const float*)d_in[5];
  const float* bf = (const float*)d_in[6];
  const float* wo = (const float*)d_in[7];
  const float* bo = (const float*)d_in[8];
  const float* wp = (const float*)d_in[9];
  const float* bp = (const float*)d_in[10];

  char* ws = (char*)d_ws;
  size_t off = 0;
  auto alloc = [&](size_t bytes) {
    char* p = ws + off;
    off += (bytes + 255) & ~(size_t)255;
    return p;
  };
  f16*   Wreg = (f16*)alloc(8388608);   // fragment-ordered W, fp16
  f16*   WPf  = (f16*)alloc(2097152);   // [1024][1024] fp16
  float* w0   = (float*)alloc(16384);   // [4][1024] x-weight col fp32
  f16*   h0   = (f16*)alloc(2097152);   // h [B][H] fp16
  f16*   h1   = (f16*)alloc(2097152);

  hipMemsetAsync(h0, 0, 2097152, stream);

  k_prep<<<2048, 256, 0, stream>>>(wg, wi, wf, wo, wp, Wreg, w0, WPf);

  {
    const f16* Wreg_c = Wreg;
    const float* w0_c = w0;
    void* args[] = {(void*)&Wreg_c, (void*)&w0_c, (void*)&x,
                    (void*)&bg, (void*)&bi, (void*)&bf, (void*)&bo,
                    (void*)&h0, (void*)&h1};
    hipLaunchCooperativeKernel((const void*)k_persist, dim3(256), dim3(512),
                               args, 0, stream);
  }
  // t=63 (odd) writes h0
  k_proj<<<64, 256, 0, stream>>>(h0, WPf, bp, (float*)d_out);
}

// Round 10
// 2914.316 us; speedup vs baseline: 1.1934x; 1.1932x over previous
//
#include <hip/hip_runtime.h>
#include <hip/hip_cooperative_groups.h>

namespace cg = cooperative_groups;

// LSTM_73512660239038: 64-step LSTM, H=B=1024, INPUT_DIM=1.
// R10: persistent cooperative kernel, W streamed through LDS (R6-proven path;
// register-W abandoned after R8/R9). 8 waves = 2rh x 2nh x 2kh: wave tile
// 64x64 over K-half 512 -> LDS fragment reads 1.5MB/step (vs 2.0 at 32x64).
// kh partials combined via two-phase z-exchange (verified R8/R9). c in VGPRs.
// XCD mapping hr=bx&31, bt=bx>>5 (R6): per-XCD W union 1MB -> L2-resident.

typedef _Float16 f16;
typedef __attribute__((ext_vector_type(8))) _Float16 f16x8;
typedef __attribute__((ext_vector_type(4))) float f32x4;

typedef const __attribute__((address_space(1))) unsigned char* gbl_ptr_t;
typedef __attribute__((address_space(3))) unsigned char* lds_ptr_t;

__device__ __forceinline__ float fsig(float z) {
  return 1.0f / (1.0f + __expf(-z));
}
__device__ __forceinline__ float ftanh(float z) {
  float a = fabsf(z);
  float e = __expf(-2.0f * a);
  float t = (1.0f - e) / (1.0f + e);
  return z < 0.0f ? -t : t;
}

// ---------------- prep: cast weights to fp16 (RNE), strip x column ----------------
__global__ __launch_bounds__(256) void k_prep(
    const float* __restrict__ wg, const float* __restrict__ wi,
    const float* __restrict__ wf, const float* __restrict__ wo,
    const float* __restrict__ wp,
    f16* __restrict__ Wf, float* __restrict__ w0, f16* __restrict__ WPf) {
  const int NW = 4 * 1024 * 1025;
  const int NP = 1024 * 1024;
  int i = blockIdx.x * blockDim.x + threadIdx.x;
  const int stride = gridDim.x * blockDim.x;
  for (; i < NW + NP; i += stride) {
    if (i < NW) {
      const int gate = i / (1024 * 1025);
      const int rem = i - gate * (1024 * 1025);
      const int r = rem / 1025;
      const int k = rem - r * 1025;
      const float* ws = gate == 0 ? wg : gate == 1 ? wi : gate == 2 ? wf : wo;
      const float v = ws[rem];
      if (k == 0) {
        w0[gate * 1024 + r] = v;            // x-weight column, fp32
      } else {
        Wf[(gate * 1024 + r) * 1024 + (k - 1)] = (f16)v;
      }
    } else {
      WPf[i - NW] = (f16)wp[i - NW];
    }
  }
}

// ---------------- persistent all-steps kernel ----------------
// grid 256 (1 block/CU): hr = bx&31 (32 h-rows), bt = bx>>5 (128 batch).
// 8 waves: kh = wid&1 (K-half), nh = (wid>>1)&1 (b-half), rh = wid>>2 (row-half).
// Wave tile 64 rows x 64 b over K = kh*512..+512. BK=64, 8 ktl iters/step.
// LDS: [0,128K) stage dbuf (64KB/set: W[2kh][128][64] + h[2kh][128][64]),
// zl [4][128][32] f32 overlays [0,64K) after K-loop; bias/w0 at 128K+.
__global__ __launch_bounds__(512) void k_persist(
    const f16* __restrict__ Wf, const float* __restrict__ w0,
    const float* __restrict__ x,
    const float* __restrict__ bg, const float* __restrict__ bi,
    const float* __restrict__ bff, const float* __restrict__ bo,
    f16* __restrict__ h0, f16* __restrict__ h1) {
  __shared__ alignas(16) unsigned char smem[133632];
  const int tid = threadIdx.x;
  const int wid = tid >> 6;
  const int lane = tid & 63;
  const int kh = wid & 1;
  const int nh = (wid >> 1) & 1;
  const int rh = wid >> 2;
  const int hr0 = (blockIdx.x & 31) * 32;
  const int b0 = (blockIdx.x >> 5) * 128;

  // ---- one-time LDS: biases + w0 slice ----
  float* zl = (float*)smem;
  float* biasl = (float*)(smem + 131072);       // [4][128]
  float* w0l = (float*)(smem + 131072 + 2048);  // [4][32]
  {
    const int g = tid >> 7, bb = tid & 127;
    const float* bsrc = g == 0 ? bg : g == 1 ? bi : g == 2 ? bff : bo;
    biasl[g * 128 + bb] = bsrc[b0 + bb];
    if (tid < 128) {
      const int g2 = tid >> 5, r = tid & 31;
      w0l[g2 * 32 + r] = w0[g2 * 1024 + hr0 + r];
    }
  }

  // ---- stage chunk decode: 4096 chunks of 16B per 64KB set, 8/thread ----
  // ch = s*512+tid: tensor=ch>>11 (0=W,1=h), khc=(ch>>10)&1, row=(ch>>3)&127,
  // sl=ch&7, sg=sl^(row&7). LDS dest linear = ch*16; global src swizzled.
  int boffW[4], boffH[4];
#pragma unroll
  for (int s = 0; s < 8; ++s) {
    const int ch = s * 512 + tid;
    const int khc = (ch >> 10) & 1;
    const int row = (ch >> 3) & 127;
    const int sl = ch & 7;
    const int sg = sl ^ (row & 7);
    if (s < 4) {
      const int gt = row >> 5, rin = row & 31;
      boffW[s] = (gt * 1024 + hr0 + rin) * 1024 + khc * 512 + sg * 8;
    } else {
      boffH[s - 4] = ((b0 + row) << 10) + khc * 512 + sg * 8;
    }
  }

  float creg[8];
#pragma unroll
  for (int q = 0; q < 8; ++q) creg[q] = 0.f;

  cg::grid_group grid = cg::this_grid();
  __syncthreads();                          // biasl/w0l ready

  const f16* Hi = h0;
  f16* Ho = h1;

#pragma unroll 1
  for (int t = 0; t < 64; ++t) {
    // ---- prologue: stage ktl=0 into buf0 ----
#pragma unroll
    for (int s = 0; s < 4; ++s)
      __builtin_amdgcn_global_load_lds((gbl_ptr_t)(const void*)(Wf + boffW[s]),
                                       (lds_ptr_t)(void*)(smem + (s * 512 + tid) * 16), 16, 0, 0);
#pragma unroll
    for (int s = 0; s < 4; ++s)
      __builtin_amdgcn_global_load_lds((gbl_ptr_t)(const void*)(Hi + boffH[s]),
                                       (lds_ptr_t)(void*)(smem + ((s + 4) * 512 + tid) * 16), 16, 0, 0);
    __syncthreads();                        // buf0 ready

    f32x4 acc[4][4];
#pragma unroll
    for (int m = 0; m < 4; ++m)
#pragma unroll
      for (int n = 0; n < 4; ++n) acc[m][n] = (f32x4){0.f, 0.f, 0.f, 0.f};

#pragma unroll
    for (int ktl = 0; ktl < 8; ++ktl) {
      const unsigned pb = (ktl & 1) * 65536;
      if (ktl < 7) {
        const unsigned nb = ((ktl + 1) & 1) * 65536;
        const int k0 = (ktl + 1) << 6;
#pragma unroll
        for (int s = 0; s < 4; ++s)
          __builtin_amdgcn_global_load_lds((gbl_ptr_t)(const void*)(Wf + boffW[s] + k0),
                                           (lds_ptr_t)(void*)(smem + nb + (s * 512 + tid) * 16), 16, 0, 0);
#pragma unroll
        for (int s = 0; s < 4; ++s)
          __builtin_amdgcn_global_load_lds((gbl_ptr_t)(const void*)(Hi + boffH[s] + k0),
                                           (lds_ptr_t)(void*)(smem + nb + ((s + 4) * 512 + tid) * 16), 16, 0, 0);
      }
      // ---- compute: wave tile 64 rows x 64 b, K-half slice kh ----
      __builtin_amdgcn_s_setprio(1);
#pragma unroll
      for (int ks = 0; ks < 2; ++ks) {
        const int slot = (ks << 2) + (lane >> 4);
        f16x8 A[4];
#pragma unroll
        for (int m = 0; m < 4; ++m) {
          const int tra = rh * 64 + m * 16 + (lane & 15);
          const unsigned offa = pb + kh * 16384 + tra * 128 + ((slot ^ (tra & 7)) << 4);
          A[m] = *(const f16x8*)(smem + offa);
        }
#pragma unroll
        for (int n = 0; n < 4; ++n) {
          const int trb = nh * 64 + n * 16 + (lane & 15);
          const unsigned offb = pb + 32768 + kh * 16384 + trb * 128 + ((slot ^ (trb & 7)) << 4);
          const f16x8 bF = *(const f16x8*)(smem + offb);
#pragma unroll
          for (int m = 0; m < 4; ++m)
            acc[m][n] = __builtin_amdgcn_mfma_f32_16x16x32_f16(A[m], bF, acc[m][n], 0, 0, 0);
        }
      }
      __builtin_amdgcn_s_setprio(0);
      __syncthreads();
    }

    // ---- z-exchange: two-phase (kh=0 write, kh=1 add), swizzled rin ----
    if (kh == 0) {
#pragma unroll
      for (int n = 0; n < 4; ++n) {
        const int b = nh * 64 + n * 16 + (lane & 15);
#pragma unroll
        for (int m = 0; m < 4; ++m)
#pragma unroll
          for (int j = 0; j < 4; ++j) {
            const int r = rh * 64 + m * 16 + (lane >> 4) * 4 + j;
            const int g = r >> 5, rin = r & 31;
            const int rs = (rin ^ ((b & 7) << 2)) ^ ((b >> 3) & 1);
            zl[g * 4096 + b * 32 + rs] = acc[m][n][j];
          }
      }
    }
    __syncthreads();
    if (kh == 1) {
#pragma unroll
      for (int n = 0; n < 4; ++n) {
        const int b = nh * 64 + n * 16 + (lane & 15);
#pragma unroll
        for (int m = 0; m < 4; ++m)
#pragma unroll
          for (int j = 0; j < 4; ++j) {
            const int r = rh * 64 + m * 16 + (lane >> 4) * 4 + j;
            const int g = r >> 5, rin = r & 31;
            const int rs = (rin ^ ((b & 7) << 2)) ^ ((b >> 3) & 1);
            zl[g * 4096 + b * 32 + rs] += acc[m][n][j];
          }
      }
    }
    __syncthreads();

    // ---- elementwise gates; bias indexed by BATCH column (ref quirk) ----
#pragma unroll
    for (int q = 0; q < 8; ++q) {
      const int idx = q * 512 + tid;
      const int r = idx & 31, bb = idx >> 5;
      const int rs = (r ^ ((bb & 7) << 2)) ^ ((bb >> 3) & 1);
      float zg = zl[bb * 32 + rs];
      float zi = zl[4096 + bb * 32 + rs];
      float zf = zl[8192 + bb * 32 + rs];
      float zo = zl[12288 + bb * 32 + rs];
      const float xv = x[(b0 + bb) * 64 + t];
      zg += w0l[r] * xv + biasl[bb];
      zi += w0l[32 + r] * xv + biasl[128 + bb];
      zf += w0l[64 + r] * xv + biasl[256 + bb];
      zo += w0l[96 + r] * xv + biasl[384 + bb];
      const float g = ftanh(zg), ii = fsig(zi), ff = fsig(zf), oo = fsig(zo);
      const float c2 = g * ii + creg[q] * ff;
      creg[q] = c2;
      const float h2 = ftanh(c2) * oo;
      Ho[(long)(b0 + bb) * 1024 + hr0 + r] = (f16)h2;
    }

    grid.sync();                            // h(t+1) visible grid-wide
    const f16* tmp = Hi;
    Hi = Ho;
    Ho = (f16*)tmp;
  }
}

// ---------------- final projection: out[b][r] = hs[b,:]·wp[r,:] + bp[r] ----------------
__global__ __launch_bounds__(256) void k_proj(
    const f16* __restrict__ H, const f16* __restrict__ WPf,
    const float* __restrict__ bp, float* __restrict__ out) {
  __shared__ alignas(16) unsigned char smem[32768];
  const int tid = threadIdx.x;
  const int wid = tid >> 6;
  const int lane = tid & 63;
  const int b0 = (blockIdx.x >> 3) * 128;   // M = batch
  const int r0 = (blockIdx.x & 7) * 128;    // N = output row

  f32x4 acc[2][8];
#pragma unroll
  for (int m = 0; m < 2; ++m)
#pragma unroll
    for (int n = 0; n < 8; ++n) acc[m][n] = (f32x4){0.f, 0.f, 0.f, 0.f};

  for (int kt = 0; kt < 16; ++kt) {
    const int k0 = kt << 6;
    __syncthreads();
#pragma unroll
    for (int j = 0; j < 4; ++j) {
      const int i = wid * 4 + j;
      const int ch = i * 64 + lane;
      const int row = ch >> 3;
      const int sl = ch & 7;
      const int sg = sl ^ (row & 7);
      const long aoff = ((long)(b0 + row) << 10) + k0 + sg * 8;
      const long boff = ((long)(r0 + row) << 10) + k0 + sg * 8;
      __builtin_amdgcn_global_load_lds((gbl_ptr_t)(const void*)(H + aoff),
                                       (lds_ptr_t)(void*)(smem + i * 1024), 16, 0, 0);
      __builtin_amdgcn_global_load_lds((gbl_ptr_t)(const void*)(WPf + boff),
                                       (lds_ptr_t)(void*)(smem + 16384 + i * 1024), 16, 0, 0);
    }
    __syncthreads();
#pragma unroll
    for (int ks = 0; ks < 2; ++ks) {
      const int slot = (ks << 2) + (lane >> 4);
      f16x8 aF[2];
#pragma unroll
      for (int m = 0; m < 2; ++m) {
        const int tr = wid * 32 + m * 16 + (lane & 15);
        const int off = tr * 128 + ((slot ^ (tr & 7)) << 4);
        aF[m] = *(const f16x8*)(smem + off);
      }
#pragma unroll
      for (int n = 0; n < 8; ++n) {
        const int tr = n * 16 + (lane & 15);
        const int off = tr * 128 + ((slot ^ (tr & 7)) << 4);
        const f16x8 bF = *(const f16x8*)(smem + 16384 + off);
#pragma unroll
        for (int m = 0; m < 2; ++m) {
          acc[m][n] = __builtin_amdgcn_mfma_f32_16x16x32_f16(aF[m], bF, acc[m][n], 0, 0, 0);
        }
      }
    }
  }
#pragma unroll
  for (int n = 0; n < 8; ++n) {
    const int rr = r0 + n * 16 + (lane & 15);
    const float bpv = bp[rr];
#pragma unroll
    for (int m = 0; m < 2; ++m) {
#pragma unroll
      for (int j = 0; j < 4; ++j) {
        const int bbb = b0 + wid * 32 + m * 16 + (lane >> 4) * 4 + j;
        out[(long)bbb * 1024 + rr] = acc[m][n][j] + bpv;
      }
    }
  }
}

extern "C" void kernel_launch(void* const* d_in, const int* in_sizes, int n_in,
                              void* d_out, int out_size, void* d_ws, size_t ws_size,
                              hipStream_t stream) {
  (void)in_sizes; (void)n_in; (void)out_size; (void)ws_size;
  const float* x  = (const float*)d_in[0];
  const float* wg = (const float*)d_in[1];
  const float* bg = (const float*)d_in[2];
  const float* wi = (const float*)d_in[3];
  const float* bi = (const float*)d_in[4];
  const float* wf = (const float*)d_in[5];
  const float* bf = (const float*)d_in[6];
  const float* wo = (const float*)d_in[7];
  const float* bo = (const float*)d_in[8];
  const float* wp = (const float*)d_in[9];
  const float* bp = (const float*)d_in[10];

  char* ws = (char*)d_ws;
  size_t off = 0;
  auto alloc = [&](size_t bytes) {
    char* p = ws + off;
    off += (bytes + 255) & ~(size_t)255;
    return p;
  };
  f16*   Wf  = (f16*)alloc(8388608);    // [4096][1024] fp16
  f16*   WPf = (f16*)alloc(2097152);    // [1024][1024] fp16
  float* w0  = (float*)alloc(16384);    // [4][1024] x-weight col fp32
  f16*   h0  = (f16*)alloc(2097152);    // h [B][H] fp16
  f16*   h1  = (f16*)alloc(2097152);

  hipMemsetAsync(h0, 0, 2097152, stream);

  k_prep<<<2048, 256, 0, stream>>>(wg, wi, wf, wo, wp, Wf, w0, WPf);

  {
    const f16* Wf_c = Wf;
    const float* w0_c = w0;
    void* args[] = {(void*)&Wf_c, (void*)&w0_c, (void*)&x,
                    (void*)&bg, (void*)&bi, (void*)&bf, (void*)&bo,
                    (void*)&h0, (void*)&h1};
    hipLaunchCooperativeKernel((const void*)k_persist, dim3(256), dim3(512),
                               args, 0, stream);
  }
  // t=63 (odd) writes h0
  k_proj<<<64, 256, 0, stream>>>(h0, WPf, bp, (float*)d_out);
}

// Round 11
// 1168.401 us; speedup vs baseline: 2.9767x; 2.4943x over previous
//
#include <hip/hip_runtime.h>

// LSTM_73512660239038: 64-step LSTM, H=B=1024, INPUT_DIM=1.
// R11 = R6 (launched per-step, best 1134us) + R10's kh-split wave tiling:
// 8 waves = 2rh x 2nh x 2kh, wave tile 64x64 over K-half 512. LDS fragment
// reads 1536 -> 1024 b128/step (the measured dominant term, 7.7 -> 5.1 us).
// kh partials combined via two-phase zl exchange (bit-exact verified R8-R10).
// Persistent/coop design abandoned (grid.sync ~30us/step straggler cost).

typedef _Float16 f16;
typedef __attribute__((ext_vector_type(8))) _Float16 f16x8;
typedef __attribute__((ext_vector_type(4))) float f32x4;

typedef const __attribute__((address_space(1))) unsigned char* gbl_ptr_t;
typedef __attribute__((address_space(3))) unsigned char* lds_ptr_t;

__device__ __forceinline__ float fsig(float z) {
  return 1.0f / (1.0f + __expf(-z));
}
__device__ __forceinline__ float ftanh(float z) {
  float a = fabsf(z);
  float e = __expf(-2.0f * a);
  float t = (1.0f - e) / (1.0f + e);
  return z < 0.0f ? -t : t;
}

// ---------------- prep: cast weights to fp16 (RNE), strip x column ----------------
__global__ __launch_bounds__(256) void k_prep(
    const float* __restrict__ wg, const float* __restrict__ wi,
    const float* __restrict__ wf, const float* __restrict__ wo,
    const float* __restrict__ wp,
    f16* __restrict__ Wf, float* __restrict__ w0, f16* __restrict__ WPf) {
  const int NW = 4 * 1024 * 1025;
  const int NP = 1024 * 1024;
  int i = blockIdx.x * blockDim.x + threadIdx.x;
  const int stride = gridDim.x * blockDim.x;
  for (; i < NW + NP; i += stride) {
    if (i < NW) {
      const int gate = i / (1024 * 1025);
      const int rem = i - gate * (1024 * 1025);
      const int r = rem / 1025;
      const int k = rem - r * 1025;
      const float* ws = gate == 0 ? wg : gate == 1 ? wi : gate == 2 ? wf : wo;
      const float v = ws[rem];
      if (k == 0) {
        w0[gate * 1024 + r] = v;            // x-weight column, fp32
      } else {
        Wf[(gate * 1024 + r) * 1024 + (k - 1)] = (f16)v;
      }
    } else {
      WPf[i - NW] = (f16)wp[i - NW];
    }
  }
}

// ---------------- per-step fused kernel (R11: kh-split tiles) ----------------
// grid 256: hr = bx&31 (32 h-rows), bt = bx>>5 (128 batch cols).
// 8 waves: kh = wid&1 (K-half), nh = (wid>>1)&1 (b-half), rh = wid>>2.
// Wave tile 64 rows x 64 b over K = kh*512..+512; BK=64 -> 8 kt iters/step.
// LDS 128KB: 2 sets x 64KB, set = W[2khc][128 row][64 k] f16 (32KB)
//            + h[2khc][128 b][64 k] f16 (32KB). zl [4][128][32] f32 overlays
// [0,64K) after the K-loop (last compute uses set1 = [64K,128K), safe).
__global__ __launch_bounds__(512) void k_step(
    const f16* __restrict__ Wf, const float* __restrict__ w0,
    const float* __restrict__ x,
    const float* __restrict__ bg, const float* __restrict__ bi,
    const float* __restrict__ bff, const float* __restrict__ bo,
    const f16* __restrict__ Hin, f16* __restrict__ Hout,
    float* __restrict__ c, int t) {
  __shared__ alignas(16) unsigned char smem[131072];
  const int tid = threadIdx.x;
  const int wid = tid >> 6;
  const int lane = tid & 63;
  const int kh = wid & 1;
  const int nh = (wid >> 1) & 1;
  const int rh = wid >> 2;
  const int hr0 = (blockIdx.x & 31) * 32;
  const int b0 = (blockIdx.x >> 5) * 128;

  // ---- stage chunk decode: 4096 chunks of 16B per 64KB set, 8/thread ----
  // ch = s*512+tid: khc=(ch>>10)&1, row=(ch>>3)&127, sl=ch&7, sg=sl^(row&7).
  // s<4 -> W region [0,32K) of set; s>=4 -> h region [32K,64K). LDS dest
  // linear = ch*16 (global_load_lds requires linear dest; swizzle on source).
  int boffW[4], boffH[4];
#pragma unroll
  for (int s = 0; s < 8; ++s) {
    const int ch = s * 512 + tid;
    const int khc = (ch >> 10) & 1;
    const int row = (ch >> 3) & 127;
    const int sl = ch & 7;
    const int sg = sl ^ (row & 7);
    if (s < 4) {
      const int gt = row >> 5, rin = row & 31;
      boffW[s] = (gt * 1024 + hr0 + rin) * 1024 + khc * 512 + sg * 8;
    } else {
      boffH[s - 4] = ((b0 + row) << 10) + khc * 512 + sg * 8;
    }
  }

  f32x4 acc[4][4];
#pragma unroll
  for (int m = 0; m < 4; ++m)
#pragma unroll
    for (int n = 0; n < 4; ++n) acc[m][n] = (f32x4){0.f, 0.f, 0.f, 0.f};

  // ---- prologue: stage kt=0 into set0 ----
#pragma unroll
  for (int s = 0; s < 4; ++s)
    __builtin_amdgcn_global_load_lds((gbl_ptr_t)(const void*)(Wf + boffW[s]),
                                     (lds_ptr_t)(void*)(smem + (s * 512 + tid) * 16), 16, 0, 0);
#pragma unroll
  for (int s = 0; s < 4; ++s)
    __builtin_amdgcn_global_load_lds((gbl_ptr_t)(const void*)(Hin + boffH[s]),
                                     (lds_ptr_t)(void*)(smem + ((s + 4) * 512 + tid) * 16), 16, 0, 0);
  __syncthreads();                          // set0 ready

#pragma unroll
  for (int kt = 0; kt < 8; ++kt) {
    const unsigned pb = (kt & 1) * 65536;
    // ---- stage kt+1 into the other set (issued BEFORE compute) ----
    if (kt < 7) {
      const unsigned nb = ((kt + 1) & 1) * 65536;
      const int k0 = (kt + 1) << 6;
#pragma unroll
      for (int s = 0; s < 4; ++s)
        __builtin_amdgcn_global_load_lds((gbl_ptr_t)(const void*)(Wf + boffW[s] + k0),
                                         (lds_ptr_t)(void*)(smem + nb + (s * 512 + tid) * 16), 16, 0, 0);
#pragma unroll
      for (int s = 0; s < 4; ++s)
        __builtin_amdgcn_global_load_lds((gbl_ptr_t)(const void*)(Hin + boffH[s] + k0),
                                         (lds_ptr_t)(void*)(smem + nb + ((s + 4) * 512 + tid) * 16), 16, 0, 0);
    }
    // ---- compute: wave tile 64 rows x 64 b, K-half slice kh ----
    __builtin_amdgcn_s_setprio(1);
#pragma unroll
    for (int ks = 0; ks < 2; ++ks) {
      const int slot = (ks << 2) + (lane >> 4);
      f16x8 A[4];
#pragma unroll
      for (int m = 0; m < 4; ++m) {
        const int tra = rh * 64 + m * 16 + (lane & 15);
        const unsigned offa = pb + kh * 16384 + tra * 128 + ((slot ^ (tra & 7)) << 4);
        A[m] = *(const f16x8*)(smem + offa);
      }
#pragma unroll
      for (int n = 0; n < 4; ++n) {
        const int trb = nh * 64 + n * 16 + (lane & 15);
        const unsigned offb = pb + 32768 + kh * 16384 + trb * 128 + ((slot ^ (trb & 7)) << 4);
        const f16x8 bF = *(const f16x8*)(smem + offb);
#pragma unroll
        for (int m = 0; m < 4; ++m)
          acc[m][n] = __builtin_amdgcn_mfma_f32_16x16x32_f16(A[m], bF, acc[m][n], 0, 0, 0);
      }
    }
    __builtin_amdgcn_s_setprio(0);
    __syncthreads();                        // next set ready; current reusable
  }

  // ---- z-exchange: two-phase (kh=0 write, kh=1 add), swizzled rin ----
  float* zl = (float*)smem;                 // [4 gates][128 b][32 r] f32 = 64KB
  if (kh == 0) {
#pragma unroll
    for (int n = 0; n < 4; ++n) {
      const int b = nh * 64 + n * 16 + (lane & 15);
#pragma unroll
      for (int m = 0; m < 4; ++m)
#pragma unroll
        for (int j = 0; j < 4; ++j) {
          const int r = rh * 64 + m * 16 + (lane >> 4) * 4 + j;
          const int g = r >> 5, rin = r & 31;
          const int rs = (rin ^ ((b & 7) << 2)) ^ ((b >> 3) & 1);
          zl[g * 4096 + b * 32 + rs] = acc[m][n][j];
        }
    }
  }
  __syncthreads();
  if (kh == 1) {
#pragma unroll
    for (int n = 0; n < 4; ++n) {
      const int b = nh * 64 + n * 16 + (lane & 15);
#pragma unroll
      for (int m = 0; m < 4; ++m)
#pragma unroll
        for (int j = 0; j < 4; ++j) {
          const int r = rh * 64 + m * 16 + (lane >> 4) * 4 + j;
          const int g = r >> 5, rin = r & 31;
          const int rs = (rin ^ ((b & 7) << 2)) ^ ((b >> 3) & 1);
          zl[g * 4096 + b * 32 + rs] += acc[m][n][j];
        }
    }
  }
  __syncthreads();

  // ---- elementwise gates; bias indexed by BATCH column (ref quirk) ----
#pragma unroll
  for (int q = 0; q < 8; ++q) {
    const int idx = q * 512 + tid;
    const int r = idx & 31, bb = idx >> 5;
    const int rs = (r ^ ((bb & 7) << 2)) ^ ((bb >> 3) & 1);
    const int gb = b0 + bb;
    const int gr = hr0 + r;
    float zg = zl[bb * 32 + rs];
    float zi = zl[4096 + bb * 32 + rs];
    float zf = zl[8192 + bb * 32 + rs];
    float zo = zl[12288 + bb * 32 + rs];
    const float xv = x[gb * 64 + t];
    zg += w0[gr] * xv + bg[gb];
    zi += w0[1024 + gr] * xv + bi[gb];
    zf += w0[2048 + gr] * xv + bff[gb];
    zo += w0[3072 + gr] * xv + bo[gb];
    const float g = ftanh(zg), ii = fsig(zi), ff = fsig(zf), oo = fsig(zo);
    const long ci = (long)gb * 1024 + gr;   // c and h stored [B][H]
    const float c2 = g * ii + c[ci] * ff;
    c[ci] = c2;
    const float h2 = ftanh(c2) * oo;
    Hout[ci] = (f16)h2;
  }
}

// ---------------- final projection: out[b][r] = hs[b,:]·wp[r,:] + bp[r] ----------------
__global__ __launch_bounds__(256) void k_proj(
    const f16* __restrict__ H, const f16* __restrict__ WPf,
    const float* __restrict__ bp, float* __restrict__ out) {
  __shared__ alignas(16) unsigned char smem[32768];
  const int tid = threadIdx.x;
  const int wid = tid >> 6;
  const int lane = tid & 63;
  const int b0 = (blockIdx.x >> 3) * 128;   // M = batch
  const int r0 = (blockIdx.x & 7) * 128;    // N = output row

  f32x4 acc[2][8];
#pragma unroll
  for (int m = 0; m < 2; ++m)
#pragma unroll
    for (int n = 0; n < 8; ++n) acc[m][n] = (f32x4){0.f, 0.f, 0.f, 0.f};

  for (int kt = 0; kt < 16; ++kt) {
    const int k0 = kt << 6;
    __syncthreads();
#pragma unroll
    for (int j = 0; j < 4; ++j) {
      const int i = wid * 4 + j;
      const int ch = i * 64 + lane;
      const int row = ch >> 3;
      const int sl = ch & 7;
      const int sg = sl ^ (row & 7);
      const long aoff = ((long)(b0 + row) << 10) + k0 + sg * 8;
      const long boff = ((long)(r0 + row) << 10) + k0 + sg * 8;
      __builtin_amdgcn_global_load_lds((gbl_ptr_t)(const void*)(H + aoff),
                                       (lds_ptr_t)(void*)(smem + i * 1024), 16, 0, 0);
      __builtin_amdgcn_global_load_lds((gbl_ptr_t)(const void*)(WPf + boff),
                                       (lds_ptr_t)(void*)(smem + 16384 + i * 1024), 16, 0, 0);
    }
    __syncthreads();
#pragma unroll
    for (int ks = 0; ks < 2; ++ks) {
      const int slot = (ks << 2) + (lane >> 4);
      f16x8 aF[2];
#pragma unroll
      for (int m = 0; m < 2; ++m) {
        const int tr = wid * 32 + m * 16 + (lane & 15);
        const int off = tr * 128 + ((slot ^ (tr & 7)) << 4);
        aF[m] = *(const f16x8*)(smem + off);
      }
#pragma unroll
      for (int n = 0; n < 8; ++n) {
        const int tr = n * 16 + (lane & 15);
        const int off = tr * 128 + ((slot ^ (tr & 7)) << 4);
        const f16x8 bF = *(const f16x8*)(smem + 16384 + off);
#pragma unroll
        for (int m = 0; m < 2; ++m) {
          acc[m][n] = __builtin_amdgcn_mfma_f32_16x16x32_f16(aF[m], bF, acc[m][n], 0, 0, 0);
        }
      }
    }
  }
#pragma unroll
  for (int n = 0; n < 8; ++n) {
    const int rr = r0 + n * 16 + (lane & 15);
    const float bpv = bp[rr];
#pragma unroll
    for (int m = 0; m < 2; ++m) {
#pragma unroll
      for (int j = 0; j < 4; ++j) {
        const int bbb = b0 + wid * 32 + m * 16 + (lane >> 4) * 4 + j;
        out[(long)bbb * 1024 + rr] = acc[m][n][j] + bpv;
      }
    }
  }
}

extern "C" void kernel_launch(void* const* d_in, const int* in_sizes, int n_in,
                              void* d_out, int out_size, void* d_ws, size_t ws_size,
                              hipStream_t stream) {
  (void)in_sizes; (void)n_in; (void)out_size; (void)ws_size;
  const float* x  = (const float*)d_in[0];
  const float* wg = (const float*)d_in[1];
  const float* bg = (const float*)d_in[2];
  const float* wi = (const float*)d_in[3];
  const float* bi = (const float*)d_in[4];
  const float* wf = (const float*)d_in[5];
  const float* bf = (const float*)d_in[6];
  const float* wo = (const float*)d_in[7];
  const float* bo = (const float*)d_in[8];
  const float* wp = (const float*)d_in[9];
  const float* bp = (const float*)d_in[10];

  char* ws = (char*)d_ws;
  size_t off = 0;
  auto alloc = [&](size_t bytes) {
    char* p = ws + off;
    off += (bytes + 255) & ~(size_t)255;
    return p;
  };
  f16*   Wf  = (f16*)alloc(8388608);    // [4096][1024] fp16
  f16*   WPf = (f16*)alloc(2097152);    // [1024][1024] fp16
  float* w0  = (float*)alloc(16384);    // [4][1024] x-weight col fp32
  f16*   h0  = (f16*)alloc(2097152);    // h [B][H] fp16
  f16*   h1  = (f16*)alloc(2097152);
  float* c   = (float*)alloc(4194304);  // [B][H] fp32

  hipMemsetAsync(h0, 0, 2097152, stream);
  hipMemsetAsync(c, 0, 4194304, stream);

  k_prep<<<2048, 256, 0, stream>>>(wg, wi, wf, wo, wp, Wf, w0, WPf);

  for (int t = 0; t < 64; ++t) {
    const f16* ih = (t & 1) ? h1 : h0;
    f16* oh = (t & 1) ? h0 : h1;
    k_step<<<256, 512, 0, stream>>>(Wf, w0, x, bg, bi, bf, bo, ih, oh, c, t);
  }
  // after t=63 (odd) the freshest h lives in buffer 0
  k_proj<<<64, 256, 0, stream>>>(h0, WPf, bp, (float*)d_out);
}